// Round 1
// baseline (415.068 us; speedup 1.0000x reference)
//
#include <hip/hip_runtime.h>
#include <hip/hip_bf16.h>

// ReBASED attention R4: Q fragments in registers (no Q LDS), 4 blocks/CU.
// QK^T computed transposed (A=K, B=Q) so the x32-MFMA C-layout IS the A-layout
// of mfma_16x16x16bf16_1k for PV -> no P LDS roundtrip.
// LDS = K/V double buffers only (37.9 KB) -> 4 blocks/CU (was 2 with Qs in LDS).
// grid=(64,8): linear id % 8 == head % 8, so all 8 q-tile blocks of a head
// share one XCD's L2 for K/V (was: head spread across all 8 XCDs).

#define SEQ 2048
#define HD  64
#define BQ  128
#define BK  64
#define LQ  72   // Ks stride in shorts (144B rows, b128-aligned cols)
#define LV  76   // Vst stride in shorts (152B rows, b64-aligned, spreads banks)

typedef __attribute__((ext_vector_type(8))) short bf16x8;
typedef __attribute__((ext_vector_type(4))) short bf16x4;
typedef __attribute__((ext_vector_type(4))) float f32x4;

__device__ inline unsigned packbf(float a, float b) {
    __hip_bfloat162 h = __float22bfloat162_rn(make_float2(a, b));  // a->low, b->high
    union { __hip_bfloat162 h2; unsigned u; } cv; cv.h2 = h; return cv.u;
}

__global__ __launch_bounds__(256, 4)
void rebased_r4_kernel(const float* __restrict__ qg,
                       const float* __restrict__ kg,
                       const float* __restrict__ vg,
                       float* __restrict__ og) {
    __shared__ __align__(16) unsigned short Ks[2][BK][LQ];
    __shared__ __align__(16) unsigned short Vst[2][HD][LV];

    const int t    = threadIdx.x;
    const int lane = t & 63;
    const int w    = t >> 6;        // wave: q-rows [w*32, w*32+32)
    const int li   = lane & 15;
    const int qd   = lane >> 4;     // quad
    const int head = blockIdx.x;    // id%8 == head%8 -> head pinned to one XCD
    const int pj   = blockIdx.y;    // 0..7 -> q-tile pair (15-pj, pj)
    const size_t base = (size_t)head * SEQ * HD;

    #pragma unroll
    for (int seg = 0; seg < 2; ++seg) {
        const int qt = seg ? pj : (15 - pj);
        const int ktmax = 2 * qt + 1;

        // ---- Q fragments straight to registers (per-wave private; scaled) ----
        bf16x8 qf[2][2];   // [ks][mt]
        {
            const int qrow0 = qt * BQ + w * 32;
            #pragma unroll
            for (int mt = 0; mt < 2; ++mt) {
                const float* qrow = qg + base + (size_t)(qrow0 + mt * 16 + li) * HD;
                #pragma unroll
                for (int ks = 0; ks < 2; ++ks) {
                    float4 a = *(const float4*)(qrow + ks * 32 + qd * 8);
                    float4 b = *(const float4*)(qrow + ks * 32 + qd * 8 + 4);
                    union { unsigned u[4]; bf16x8 v; } cv;
                    cv.u[0] = packbf(a.x * 0.125f, a.y * 0.125f);
                    cv.u[1] = packbf(a.z * 0.125f, a.w * 0.125f);
                    cv.u[2] = packbf(b.x * 0.125f, b.y * 0.125f);
                    cv.u[3] = packbf(b.z * 0.125f, b.w * 0.125f);
                    qf[ks][mt] = cv.v;
                }
            }
        }

        // ---- load kt=0 K/V into registers ----
        float4 kreg[4], vreg[4];
        {
            const float4* ksrc = (const float4*)(kg + base);
            const float4* vsrc = (const float4*)(vg + base);
            #pragma unroll
            for (int l = 0; l < 4; ++l) kreg[l] = ksrc[t + l * 256];
            const int d4g = t & 15, rp = t >> 4;
            #pragma unroll
            for (int p = 0; p < 2; ++p) {
                int r0 = p * 32 + rp * 2;
                vreg[2 * p]     = vsrc[r0 * 16 + d4g];
                vreg[2 * p + 1] = vsrc[(r0 + 1) * 16 + d4g];
            }
        }
        __syncthreads();   // prior segment's LDS reads complete

        // ---- write kt=0 K/V to LDS ----
        #pragma unroll
        for (int l = 0; l < 4; ++l) {
            int row = (t >> 4) + l * 16, d4 = (t & 15) << 2;
            unsigned* dst = (unsigned*)&Ks[0][row][d4];
            dst[0] = packbf(kreg[l].x, kreg[l].y);
            dst[1] = packbf(kreg[l].z, kreg[l].w);
        }
        {
            const int d4g = t & 15, rp = t >> 4;
            #pragma unroll
            for (int p = 0; p < 2; ++p) {
                int r0 = p * 32 + rp * 2;
                float a0[4] = {vreg[2*p].x, vreg[2*p].y, vreg[2*p].z, vreg[2*p].w};
                float a1[4] = {vreg[2*p+1].x, vreg[2*p+1].y, vreg[2*p+1].z, vreg[2*p+1].w};
                #pragma unroll
                for (int j = 0; j < 4; ++j)
                    *(unsigned*)&Vst[0][d4g * 4 + j][r0] = packbf(a0[j], a1[j]);
            }
        }
        __syncthreads();

        f32x4 oacc[2][4];
        float zpart[2] = {0.f, 0.f};
        #pragma unroll
        for (int mt = 0; mt < 2; ++mt)
            #pragma unroll
            for (int nd = 0; nd < 4; ++nd) oacc[mt][nd] = (f32x4){0.f, 0.f, 0.f, 0.f};

        for (int kt = 0; kt <= ktmax; ++kt) {
            const int cur = kt & 1;

            // ---- prefetch kt+1 K/V into registers (latency hides under compute) ----
            if (kt < ktmax) {
                const float4* ksrc = (const float4*)(kg + base + (size_t)(kt + 1) * BK * HD);
                const float4* vsrc = (const float4*)(vg + base + (size_t)(kt + 1) * BK * HD);
                #pragma unroll
                for (int l = 0; l < 4; ++l) kreg[l] = ksrc[t + l * 256];
                const int d4g = t & 15, rp = t >> 4;
                #pragma unroll
                for (int p = 0; p < 2; ++p) {
                    int r0 = p * 32 + rp * 2;
                    vreg[2 * p]     = vsrc[r0 * 16 + d4g];
                    vreg[2 * p + 1] = vsrc[(r0 + 1) * 16 + d4g];
                }
            }

            const int qrow_min = qt * BQ + w * 32;
            const bool active   = (kt * BK <= qrow_min + 31);
            const bool needmask = (kt * BK + 63 > qrow_min);

            if (active) {
                // ---- S^T = K·Q^T : x32 MFMA, A=K-frag (LDS), B=Q-frag (regs) ----
                f32x4 stt[4][2];
                #pragma unroll
                for (int nk = 0; nk < 4; ++nk)
                    #pragma unroll
                    for (int mt = 0; mt < 2; ++mt) stt[nk][mt] = (f32x4){0.f,0.f,0.f,0.f};
                #pragma unroll
                for (int ks = 0; ks < 2; ++ks) {
                    const int kb = ks * 32 + qd * 8;
                    bf16x8 kf[4];
                    #pragma unroll
                    for (int nk = 0; nk < 4; ++nk)
                        kf[nk] = *(const bf16x8*)&Ks[cur][nk * 16 + li][kb];
                    #pragma unroll
                    for (int nk = 0; nk < 4; ++nk)
                        #pragma unroll
                        for (int mt = 0; mt < 2; ++mt)
                            stt[nk][mt] = __builtin_amdgcn_mfma_f32_16x16x32_bf16(
                                kf[nk], qf[ks][mt], stt[nk][mt], 0, 0, 0);
                }

                // ---- square + mask + pack: C-layout of S^T == A-layout for x16 MFMA ----
                unsigned pk[4][2][2];
                #pragma unroll
                for (int nk = 0; nk < 4; ++nk) {
                    const int kcb = kt * BK + nk * 16 + qd * 4;
                    #pragma unroll
                    for (int mt = 0; mt < 2; ++mt) {
                        const int qrow = qrow_min + mt * 16 + li;
                        float p[4];
                        #pragma unroll
                        for (int r = 0; r < 4; ++r) {
                            float s = stt[nk][mt][r];
                            if (needmask && (kcb + r > qrow)) s = 0.f;
                            p[r] = s * s;
                        }
                        zpart[mt] += (p[0] + p[1]) + (p[2] + p[3]);
                        pk[nk][mt][0] = packbf(p[0], p[1]);
                        pk[nk][mt][1] = packbf(p[2], p[3]);
                    }
                }

                // ---- O += P·V : x16 MFMA, A=P (in regs), B=V^T from LDS ----
                #pragma unroll
                for (int ks16 = 0; ks16 < 4; ++ks16) {
                    bf16x4 av[2];
                    #pragma unroll
                    for (int mt = 0; mt < 2; ++mt) {
                        union { unsigned u[2]; bf16x4 v; } cv;
                        cv.u[0] = pk[ks16][mt][0]; cv.u[1] = pk[ks16][mt][1];
                        av[mt] = cv.v;
                    }
                    #pragma unroll
                    for (int nd = 0; nd < 4; ++nd) {
                        bf16x4 vf = *(const bf16x4*)&Vst[cur][nd * 16 + li][ks16 * 16 + qd * 4];
                        #pragma unroll
                        for (int mt = 0; mt < 2; ++mt)
                            oacc[mt][nd] = __builtin_amdgcn_mfma_f32_16x16x16bf16_1k(
                                av[mt], vf, oacc[mt][nd], 0, 0, 0);
                    }
                }
            }

            // ---- write prefetched kt+1 into the other buffer ----
            if (kt < ktmax) {
                const int nb = cur ^ 1;
                #pragma unroll
                for (int l = 0; l < 4; ++l) {
                    int row = (t >> 4) + l * 16, d4 = (t & 15) << 2;
                    unsigned* dst = (unsigned*)&Ks[nb][row][d4];
                    dst[0] = packbf(kreg[l].x, kreg[l].y);
                    dst[1] = packbf(kreg[l].z, kreg[l].w);
                }
                const int d4g = t & 15, rp = t >> 4;
                #pragma unroll
                for (int p = 0; p < 2; ++p) {
                    int r0 = p * 32 + rp * 2;
                    float a0[4] = {vreg[2*p].x, vreg[2*p].y, vreg[2*p].z, vreg[2*p].w};
                    float a1[4] = {vreg[2*p+1].x, vreg[2*p+1].y, vreg[2*p+1].z, vreg[2*p+1].w};
                    #pragma unroll
                    for (int j = 0; j < 4; ++j)
                        *(unsigned*)&Vst[nb][d4g * 4 + j][r0] = packbf(a0[j], a1[j]);
                }
            }
            __syncthreads();
        }

        // ---- epilogue: z reduce (quads) + divide + store ----
        float* odst = og + base + (size_t)qt * BQ * HD;
        #pragma unroll
        for (int mt = 0; mt < 2; ++mt) {
            float zf = zpart[mt];
            zf += __shfl_xor(zf, 16, 64);
            zf += __shfl_xor(zf, 32, 64);   // all lanes: z for qrow = mt*16 + li
            #pragma unroll
            for (int r = 0; r < 4; ++r) {
                float zr = __shfl(zf, qd * 4 + r, 64);
                float inv = 1.f / (zr + 1e-6f);
                int row = w * 32 + mt * 16 + qd * 4 + r;
                #pragma unroll
                for (int nd = 0; nd < 4; ++nd)
                    odst[row * HD + nd * 16 + li] = oacc[mt][nd][r] * inv;
            }
        }
    }
}

extern "C" void kernel_launch(void* const* d_in, const int* in_sizes, int n_in,
                              void* d_out, int out_size, void* d_ws, size_t ws_size,
                              hipStream_t stream) {
    const float* q = (const float*)d_in[0];
    const float* k = (const float*)d_in[1];
    const float* v = (const float*)d_in[2];
    float* out = (float*)d_out;

    dim3 grid(64, 8);    // head-major: all 8 q-tile blocks of a head on one XCD
    dim3 block(256);
    rebased_r4_kernel<<<grid, block, 0, stream>>>(q, k, v, out);
}